// Round 1
// baseline (51471.362 us; speedup 1.0000x reference)
//
#include <hip/hip_runtime.h>
#include <math.h>

#define T_LEN 512
#define BATCH 128
#define HID   256
#define GATES (4*HID)   // 1024

__device__ __forceinline__ float sigmoid_f(float v) {
    return 1.f / (1.f + __expf(-v));
}

__device__ __forceinline__ float tanh_f(float v) {
    v = fminf(fmaxf(v, -15.f), 15.f);   // avoid inf/inf -> NaN
    float e = __expf(2.f * v);
    return (e - 1.f) / (e + 1.f);
}

__device__ __forceinline__ float4 ldf4(const float* p) {
    return *reinterpret_cast<const float4*>(p);
}

__device__ __forceinline__ void fma4(float4& a, const float4 v, const float4 w) {
    a.x = fmaf(v.x, w.x, a.x);
    a.y = fmaf(v.y, w.y, a.y);
    a.z = fmaf(v.z, w.z, a.z);
    a.w = fmaf(v.w, w.w, a.w);
}

__device__ __forceinline__ float hsum4(const float4 a) {
    return (a.x + a.y) + (a.z + a.w);
}

// Poison-proof grid barrier: flags/release start as 0xAAAAAAAA (ws poison);
// we only ever test equality against gen in [1, 512], so no init needed.
// Master block (bid 0) polls all 256 flags with its 256 threads.
__device__ __forceinline__ void grid_barrier(unsigned* flags, unsigned* release,
                                             unsigned gen, int bid, int tid) {
    __threadfence();   // release: drain h stores, writeback L2 so other XCDs can see them
    __syncthreads();
    if (bid == 0) {
        if (tid == 0)
            __hip_atomic_store(&flags[0], gen, __ATOMIC_RELAXED, __HIP_MEMORY_SCOPE_AGENT);
        while (__hip_atomic_load(&flags[tid], __ATOMIC_RELAXED, __HIP_MEMORY_SCOPE_AGENT) != gen)
            __builtin_amdgcn_s_sleep(2);
        __syncthreads();
        if (tid == 0)
            __hip_atomic_store(release, gen, __ATOMIC_RELAXED, __HIP_MEMORY_SCOPE_AGENT);
    } else {
        if (tid == 0) {
            __hip_atomic_store(&flags[bid], gen, __ATOMIC_RELAXED, __HIP_MEMORY_SCOPE_AGENT);
            while (__hip_atomic_load(release, __ATOMIC_RELAXED, __HIP_MEMORY_SCOPE_AGENT) != gen)
                __builtin_amdgcn_s_sleep(2);
        }
        __syncthreads();
    }
    __threadfence();   // acquire: invalidate L1/L2 so fresh h is visible
}

// Persistent pipelined LSTM.
// Blocks 0..127: layer 0 (time t = s), blocks 128..255: layer 1 (time t = s-1).
// Block tile: 16 batch x 16 hidden. Thread: one (b, j) output, 4 gate dots.
// h state triple-buffered in ws (slot = s % 3); c state lives in a register.
__global__ __launch_bounds__(256) void lstm_persist(
    const float* __restrict__ x,
    const float* __restrict__ Wih,
    const float* __restrict__ Whh,
    const float* __restrict__ bih,
    const float* __restrict__ bhh,
    float* __restrict__ out,
    float* __restrict__ h0buf,   // 3 * B * H
    float* __restrict__ h1buf,   // 3 * B * H
    unsigned* __restrict__ flags,
    unsigned* __restrict__ release)
{
    const int bid = blockIdx.x;
    const int tid = threadIdx.x;
    const int layer = bid >> 7;          // 0 or 1
    const int r = bid & 127;
    const int jt = r & 15;               // 16 j-tiles
    const int bt = r >> 4;               // 8 b-tiles
    const int jj = tid & 15;             // j fast within wave (store coalescing)
    const int bb = tid >> 4;
    const int b = bt * 16 + bb;          // 0..127
    const int j = jt * 16 + jj;          // 0..255

    const float* Wih_l = Wih + (size_t)layer * GATES * HID;
    const float* Whh_l = Whh + (size_t)layer * GATES * HID;
    const float* wi0 = Wih_l + (size_t)(0 * HID + j) * HID;
    const float* wi1 = Wih_l + (size_t)(1 * HID + j) * HID;
    const float* wi2 = Wih_l + (size_t)(2 * HID + j) * HID;
    const float* wi3 = Wih_l + (size_t)(3 * HID + j) * HID;
    const float* wh0 = Whh_l + (size_t)(0 * HID + j) * HID;
    const float* wh1 = Whh_l + (size_t)(1 * HID + j) * HID;
    const float* wh2 = Whh_l + (size_t)(2 * HID + j) * HID;
    const float* wh3 = Whh_l + (size_t)(3 * HID + j) * HID;

    const float bias0 = bih[layer * GATES + 0 * HID + j] + bhh[layer * GATES + 0 * HID + j];
    const float bias1 = bih[layer * GATES + 1 * HID + j] + bhh[layer * GATES + 1 * HID + j];
    const float bias2 = bih[layer * GATES + 2 * HID + j] + bhh[layer * GATES + 2 * HID + j];
    const float bias3 = bih[layer * GATES + 3 * HID + j] + bhh[layer * GATES + 3 * HID + j];

    float c = 0.f;
    float hlast = 0.f;

    for (int s = 0; s <= T_LEN; ++s) {
        const bool active = (layer == 0) ? (s < T_LEN) : (s >= 1);
        if (active) {
            const int t = (layer == 0) ? s : (s - 1);
            // part-1 input: layer0 <- x[t]; layer1 <- h0 published last super-step
            const float* in1 = (layer == 0)
                ? (x + (size_t)s * BATCH * HID)
                : (h0buf + (size_t)((s - 1) % 3) * BATCH * HID);
            // part-2 input: own layer h state from previous timestep
            const float* hprev = (layer == 0)
                ? (h0buf + (size_t)((s - 1) % 3) * BATCH * HID)
                : (h1buf + (size_t)((s - 1) % 3) * BATCH * HID);
            const bool skip2 = (layer == 0) ? (s == 0) : (s == 1);  // h starts at 0

            float4 a0 = {0.f, 0.f, 0.f, 0.f};
            float4 a1 = {0.f, 0.f, 0.f, 0.f};
            float4 a2 = {0.f, 0.f, 0.f, 0.f};
            float4 a3 = {0.f, 0.f, 0.f, 0.f};

            const float* inb = in1 + (size_t)b * HID;
            #pragma unroll 4
            for (int k = 0; k < HID; k += 4) {
                const float4 v = ldf4(inb + k);
                fma4(a0, v, ldf4(wi0 + k));
                fma4(a1, v, ldf4(wi1 + k));
                fma4(a2, v, ldf4(wi2 + k));
                fma4(a3, v, ldf4(wi3 + k));
            }
            if (!skip2) {
                const float* hb = hprev + (size_t)b * HID;
                #pragma unroll 4
                for (int k = 0; k < HID; k += 4) {
                    const float4 v = ldf4(hb + k);
                    fma4(a0, v, ldf4(wh0 + k));
                    fma4(a1, v, ldf4(wh1 + k));
                    fma4(a2, v, ldf4(wh2 + k));
                    fma4(a3, v, ldf4(wh3 + k));
                }
            }

            const float gi = sigmoid_f(bias0 + hsum4(a0));
            const float gf = sigmoid_f(bias1 + hsum4(a1));
            const float gg = tanh_f   (bias2 + hsum4(a2));
            const float go = sigmoid_f(bias3 + hsum4(a3));
            c = fmaf(gf, c, gi * gg);
            const float h = go * tanh_f(c);
            hlast = h;

            float* myout = (layer == 0)
                ? (h0buf + (size_t)(s % 3) * BATCH * HID)
                : (h1buf + (size_t)(s % 3) * BATCH * HID);
            myout[(size_t)b * HID + j] = h;
            if (layer == 1)
                out[(size_t)t * BATCH * HID + (size_t)b * HID + j] = h;
        }
        if (s < T_LEN)
            grid_barrier(flags, release, (unsigned)(s + 1), bid, tid);
    }

    // finals: h_n, c_n
    float* hn = out + (size_t)T_LEN * BATCH * HID;
    float* cn = hn + 2 * BATCH * HID;
    hn[(size_t)layer * BATCH * HID + (size_t)b * HID + j] = hlast;
    cn[(size_t)layer * BATCH * HID + (size_t)b * HID + j] = c;
}

extern "C" void kernel_launch(void* const* d_in, const int* in_sizes, int n_in,
                              void* d_out, int out_size, void* d_ws, size_t ws_size,
                              hipStream_t stream) {
    const float* x   = (const float*)d_in[0];
    const float* Wih = (const float*)d_in[1];
    const float* Whh = (const float*)d_in[2];
    const float* bih = (const float*)d_in[3];
    const float* bhh = (const float*)d_in[4];
    float* out = (float*)d_out;

    float* h0 = (float*)d_ws;                     // 3*B*H floats
    float* h1 = h0 + 3 * BATCH * HID;             // 3*B*H floats
    unsigned* flags   = (unsigned*)(h1 + 3 * BATCH * HID);
    unsigned* release = flags + 256;

    hipLaunchKernelGGL(lstm_persist, dim3(256), dim3(256), 0, stream,
                       x, Wih, Whh, bih, bhh, out, h0, h1, flags, release);
}

// Round 2
// 7310.592 us; speedup vs baseline: 7.0407x; 7.0407x over previous
//
#include <hip/hip_runtime.h>
#include <math.h>

#define T_LEN 512
#define BATCH 128
#define HID   256
#define BH    (BATCH*HID)   // 32768

// ---------------- helpers ----------------
__device__ __forceinline__ float sigmoid_f(float v) {
    return 1.f / (1.f + __expf(-v));
}
__device__ __forceinline__ float tanh_f(float v) {
    v = fminf(fmaxf(v, -15.f), 15.f);
    float e = __expf(2.f * v);
    return (e - 1.f) / (e + 1.f);
}
__device__ __forceinline__ float4 ldf4(const float* p) {
    return *reinterpret_cast<const float4*>(p);
}
__device__ __forceinline__ void fma4(float4& a, const float4 v, const float4 w) {
    a.x = fmaf(v.x, w.x, a.x);
    a.y = fmaf(v.y, w.y, a.y);
    a.z = fmaf(v.z, w.z, a.z);
    a.w = fmaf(v.w, w.w, a.w);
}
__device__ __forceinline__ float hsum4(const float4 a) {
    return (a.x + a.y) + (a.z + a.w);
}
// agent-scope relaxed atomics: coherent across XCDs, no cache flushes
__device__ __forceinline__ float aload(const float* p) {
    return __hip_atomic_load(p, __ATOMIC_RELAXED, __HIP_MEMORY_SCOPE_AGENT);
}
__device__ __forceinline__ void astore(float* p, float v) {
    __hip_atomic_store(p, v, __ATOMIC_RELAXED, __HIP_MEMORY_SCOPE_AGENT);
}
__device__ __forceinline__ float4 af4(const float* p) {
    float4 v;
    v.x = aload(p + 0); v.y = aload(p + 1);
    v.z = aload(p + 2); v.w = aload(p + 3);
    return v;
}
// DPP row_shr prefix reduction within 16-lane groups; lane (kc==15) gets the sum.
template<int CTRL>
__device__ __forceinline__ float dpp_mv(float x) {
    return __int_as_float(__builtin_amdgcn_update_dpp(
        0, __float_as_int(x), CTRL, 0xF, 0xF, true));
}
__device__ __forceinline__ float red16(float x) {
    x += dpp_mv<0x111>(x);  // row_shr:1
    x += dpp_mv<0x112>(x);  // row_shr:2
    x += dpp_mv<0x114>(x);  // row_shr:4
    x += dpp_mv<0x118>(x);  // row_shr:8
    return x;               // valid in lane kc==15 of each 16-group
}

// ---------------- persistent LSTM ----------------
// grid 256 x 256. layer = bid>>7, jt = (bid>>4)&7 (32 j each), bg = bid&15 (8 b each).
// bid%8 == bg%8 -> sync group tends to share an XCD (perf heuristic only).
// tid: jp = tid>>4, kc = tid&15. Thread owns j0=jt*32+jp, j1=j0+16; all 4 gates;
// K-chunk [kc*32, kc*32+32) of combined K=512 ([0,256)=input/lower layer, [256,512)=recurrent).
// Weights: 8 rows x 32 floats = 256 VGPRs, loaded once. c-state in LDS.
__global__ __launch_bounds__(256, 1) void lstm_persist(
    const float* __restrict__ x,
    const float* __restrict__ Wih, const float* __restrict__ Whh,
    const float* __restrict__ bih, const float* __restrict__ bhh,
    float* __restrict__ out,
    float* __restrict__ h0buf,   // 3 * BH (triple-buffered by timestep%3)
    float* __restrict__ h1buf,   // 3 * BH
    int* __restrict__ flags)     // 16 groups x 16 blocks
{
    __shared__ float ls_in[8 * 576];   // 8 b x 16 chunks x 36 (pad: 32+4 -> 2-way bank alias = free)
    __shared__ float ls_c[256];        // c[b][jp][js]

    const int tid = threadIdx.x;
    const int bid = blockIdx.x;
    const int layer = bid >> 7;
    const int jt = (bid >> 4) & 7;
    const int bg = bid & 15;
    const int jp = tid >> 4;
    const int kc = tid & 15;
    const int Bg0 = bg * 8;

    const float* Wih_l = Wih + (size_t)layer * 4 * HID * HID;
    const float* Whh_l = Whh + (size_t)layer * 4 * HID * HID;
    const float* bih_l = bih + layer * 4 * HID;
    const float* bhh_l = bhh + layer * 4 * HID;

    float4 w[8][8];     // [r = js*4+g][m]
    float bias[8];
    #pragma unroll
    for (int r = 0; r < 8; ++r) {
        const int js = r >> 2, g = r & 3;
        const int jx = jt * 32 + jp + js * 16;
        const int row = g * HID + jx;            // row in 4H
        const float* base = (kc < 8)
            ? (Wih_l + (size_t)row * HID + kc * 32)
            : (Whh_l + (size_t)row * HID + (kc - 8) * 32);
        #pragma unroll
        for (int m = 0; m < 8; ++m) w[r][m] = ldf4(base + m * 4);
        bias[r] = bih_l[row] + bhh_l[row];
    }

    ls_c[tid] = 0.f;   // synced before first use by the staging barrier below

    int* myflag = flags + bg * 16 + layer * 8 + jt;

    #pragma unroll 1
    for (int s = 0; s <= T_LEN; ++s) {
        if (s > 0 && tid < 16) {
            const int* f = flags + bg * 16 + tid;
            // signed compare: 0xAAAAAAAA poison is negative -> blocks until real store
            while (__hip_atomic_load(f, __ATOMIC_RELAXED, __HIP_MEMORY_SCOPE_AGENT) < s)
                __builtin_amdgcn_s_sleep(1);
        }
        __syncthreads();   // everyone past poll; h[s-1] published & visible

        const bool active = (layer == 0) ? (s < T_LEN) : (s >= 1);
        if (active) {
            // ---- stage [x|h] (combined K=512) for our 8 batch rows into LDS ----
            const bool zero2 = (layer == 0) ? (s == 0) : (s == 1);
            const float* p1 = (layer == 0)
                ? (x + (size_t)s * BH)
                : (h0buf + (size_t)((s + 2) % 3) * BH);   // h0[s-1]
            const float* p2 = (layer == 0)
                ? (h0buf + (size_t)((s + 2) % 3) * BH)    // h0[s-1]
                : (h1buf + (size_t)((s + 1) % 3) * BH);   // h1[s-2]
            #pragma unroll
            for (int i = 0; i < 4; ++i) {
                const int F = tid + 256 * i;     // f4 index in 8x128
                const int b = F >> 7;
                const int rr = F & 127;
                const int col = (rr & 63) * 4;
                float4 v;
                if ((rr >> 6) == 0) {
                    const float* src = p1 + (size_t)(Bg0 + b) * HID + col;
                    v = (layer == 0) ? ldf4(src) : af4(src);
                } else if (zero2) {
                    v = make_float4(0.f, 0.f, 0.f, 0.f);
                } else {
                    const float* src = p2 + (size_t)(Bg0 + b) * HID + col;
                    v = af4(src);
                }
                *(float4*)(ls_in + b * 576 + (rr >> 3) * 36 + (rr & 7) * 4) = v;
            }
        }
        __syncthreads();   // staging visible

        if (active) {
            const int t_s = (layer == 0) ? s : (s - 1);
            float* hst = ((layer == 0) ? h0buf : h1buf) + (size_t)(t_s % 3) * BH;
            const bool last = (layer == 0) ? (s == T_LEN - 1) : (s == T_LEN);
            #pragma unroll 1
            for (int b = 0; b < 8; ++b) {
                const float* Lp = ls_in + b * 576 + kc * 36;
                float4 in[8];
                #pragma unroll
                for (int m = 0; m < 8; ++m) in[m] = *(const float4*)(Lp + m * 4);
                float4 ac[8];
                #pragma unroll
                for (int r = 0; r < 8; ++r) ac[r] = make_float4(0.f, 0.f, 0.f, 0.f);
                #pragma unroll
                for (int m = 0; m < 8; ++m) {
                    #pragma unroll
                    for (int r = 0; r < 8; ++r) fma4(ac[r], in[m], w[r][m]);
                }
                float a[8];
                #pragma unroll
                for (int r = 0; r < 8; ++r) a[r] = red16(hsum4(ac[r]));
                if (kc == 15) {        // owner lane holds full K-sum
                    const int B = Bg0 + b;
                    float* cp = ls_c + b * 32 + jp * 2;
                    #pragma unroll
                    for (int js = 0; js < 2; ++js) {
                        const int r0 = js * 4;
                        const float gi = sigmoid_f(a[r0 + 0] + bias[r0 + 0]);
                        const float gf = sigmoid_f(a[r0 + 1] + bias[r0 + 1]);
                        const float gg = tanh_f   (a[r0 + 2] + bias[r0 + 2]);
                        const float go = sigmoid_f(a[r0 + 3] + bias[r0 + 3]);
                        const float cnew = fmaf(gf, cp[js], gi * gg);
                        cp[js] = cnew;
                        const float h = go * tanh_f(cnew);
                        const int jg = jt * 32 + jp + js * 16;
                        astore(hst + (size_t)B * HID + jg, h);
                        if (layer == 1)
                            out[(size_t)t_s * BH + (size_t)B * HID + jg] = h;
                        if (last) {
                            float* hn  = out + (size_t)T_LEN * BH;
                            float* cnp = hn + 2 * BH;
                            hn [(size_t)layer * BH + (size_t)B * HID + jg] = h;
                            cnp[(size_t)layer * BH + (size_t)B * HID + jg] = cnew;
                        }
                    }
                }
            }
        }
        __syncthreads();   // all waves' h-stores drained (implicit vmcnt(0) before s_barrier)
        if (s < T_LEN && tid == 0)
            __hip_atomic_store(myflag, s + 1, __ATOMIC_RELAXED, __HIP_MEMORY_SCOPE_AGENT);
    }
}

extern "C" void kernel_launch(void* const* d_in, const int* in_sizes, int n_in,
                              void* d_out, int out_size, void* d_ws, size_t ws_size,
                              hipStream_t stream) {
    const float* x   = (const float*)d_in[0];
    const float* Wih = (const float*)d_in[1];
    const float* Whh = (const float*)d_in[2];
    const float* bih = (const float*)d_in[3];
    const float* bhh = (const float*)d_in[4];
    float* out = (float*)d_out;

    float* h0 = (float*)d_ws;          // 3*BH
    float* h1 = h0 + 3 * BH;           // 3*BH
    int* flags = (int*)(h1 + 3 * BH);  // 256 ints, poison-proof (signed compare)

    hipLaunchKernelGGL(lstm_persist, dim3(256), dim3(256), 0, stream,
                       x, Wih, Whh, bih, bhh, out, h0, h1, flags);
}

// Round 3
// 5316.468 us; speedup vs baseline: 9.6815x; 1.3751x over previous
//
#include <hip/hip_runtime.h>
#include <math.h>

#define T_LEN 512
#define BATCH 128
#define HID   256
#define BH    (BATCH*HID)   // 32768

// ---------------- helpers ----------------
__device__ __forceinline__ float sigmoid_f(float v) {
    return 1.f / (1.f + __expf(-v));
}
__device__ __forceinline__ float tanh_f(float v) {
    v = fminf(fmaxf(v, -15.f), 15.f);
    float e = __expf(2.f * v);
    return (e - 1.f) / (e + 1.f);
}
__device__ __forceinline__ float4 ldf4(const float* p) {
    return *reinterpret_cast<const float4*>(p);
}
__device__ __forceinline__ void fma4(float4& a, const float4 v, const float4 w) {
    a.x = fmaf(v.x, w.x, a.x);
    a.y = fmaf(v.y, w.y, a.y);
    a.z = fmaf(v.z, w.z, a.z);
    a.w = fmaf(v.w, w.w, a.w);
}
__device__ __forceinline__ float hsum4(const float4 a) {
    return (a.x + a.y) + (a.z + a.w);
}
// agent-scope relaxed atomics: coherent across XCDs, no cache flushes
__device__ __forceinline__ void astore(float* p, float v) {
    __hip_atomic_store(p, v, __ATOMIC_RELAXED, __HIP_MEMORY_SCOPE_AGENT);
}
__device__ __forceinline__ float2 af2(const float* p) {
    unsigned long long u = __hip_atomic_load((const unsigned long long*)p,
                                             __ATOMIC_RELAXED, __HIP_MEMORY_SCOPE_AGENT);
    union { unsigned long long u; float2 f; } c; c.u = u;
    return c.f;
}
__device__ __forceinline__ float4 af4(const float* p) {
    const float2 a = af2(p), b = af2(p + 2);
    return make_float4(a.x, a.y, b.x, b.y);
}
// DPP row_shr prefix reduction within 16-lane groups; lane (kc==15) gets the sum.
template<int CTRL>
__device__ __forceinline__ float dpp_mv(float x) {
    return __int_as_float(__builtin_amdgcn_update_dpp(
        0, __float_as_int(x), CTRL, 0xF, 0xF, true));
}
__device__ __forceinline__ float red16(float x) {
    x += dpp_mv<0x111>(x);  // row_shr:1
    x += dpp_mv<0x112>(x);  // row_shr:2
    x += dpp_mv<0x114>(x);  // row_shr:4
    x += dpp_mv<0x118>(x);  // row_shr:8
    return x;               // valid in lane kc==15 of each 16-group
}

// ---------------- persistent LSTM ----------------
// grid 512 x 256, 2 blocks/CU (launch_bounds(256,2) -> VGPR cap 256, no spill).
// bid: bg = bid&15 (8 batch rows), layer = (bid>>4)&1, jt = bid>>5 (16 j each).
// Same-bg sync group (32 blocks) lands on one XCD via round-robin dispatch.
// tid: jp = tid>>4 (one j per thread), kc = tid&15 (K-chunk of 32 in combined
// K=512: [0,256)=input/lower-layer h, [256,512)=own recurrent h).
// Weights: 4 gate rows x 32 floats = 128 VGPRs/thread, loaded once.
__global__ __launch_bounds__(256, 2) void lstm_persist(
    const float* __restrict__ x,
    const float* __restrict__ Wih, const float* __restrict__ Whh,
    const float* __restrict__ bih, const float* __restrict__ bhh,
    float* __restrict__ out,
    float* __restrict__ h0buf,   // 3 * BH (triple-buffered by timestep%3)
    float* __restrict__ h1buf,   // 3 * BH
    int* __restrict__ flags)     // 16 groups x 32 blocks
{
    __shared__ float ls_in[8 * 576];   // 8 b x 16 chunks x 36 (pad -> 2-way alias = free)
    __shared__ float ls_c[128];        // c[b][jp]

    const int tid = threadIdx.x;
    const int bid = blockIdx.x;
    const int bg = bid & 15;
    const int layer = (bid >> 4) & 1;
    const int jt = bid >> 5;
    const int jp = tid >> 4;
    const int kc = tid & 15;
    const int j = jt * 16 + jp;
    const int Bg0 = bg * 8;

    const float* Wih_l = Wih + (size_t)layer * 4 * HID * HID;
    const float* Whh_l = Whh + (size_t)layer * 4 * HID * HID;
    const float* bih_l = bih + layer * 4 * HID;
    const float* bhh_l = bhh + layer * 4 * HID;

    float4 w[4][8];     // [gate][m] : 128 VGPRs
    float bias[4];
    #pragma unroll
    for (int g = 0; g < 4; ++g) {
        const int row = g * HID + j;             // row in 4H
        const float* base = (kc < 8)
            ? (Wih_l + (size_t)row * HID + kc * 32)
            : (Whh_l + (size_t)row * HID + (kc - 8) * 32);
        #pragma unroll
        for (int m = 0; m < 8; ++m) w[g][m] = ldf4(base + m * 4);
        bias[g] = bih_l[row] + bhh_l[row];
    }

    if (tid < 128) ls_c[tid] = 0.f;   // synced by first barrier below

    int* myflag = flags + bg * 32 + layer * 16 + jt;

    #pragma unroll 1
    for (int s = 0; s <= T_LEN; ++s) {
        if (s > 0 && tid < 32) {
            const int* f = flags + bg * 32 + tid;
            // signed compare: 0xAAAAAAAA poison is negative -> blocks until real store
            while (__hip_atomic_load(f, __ATOMIC_RELAXED, __HIP_MEMORY_SCOPE_AGENT) < s)
                __builtin_amdgcn_s_sleep(1);
        }
        __syncthreads();   // everyone past poll; h[s-1] published & visible

        const bool active = (layer == 0) ? (s < T_LEN) : (s >= 1);
        if (active) {
            // ---- stage [x|h] (combined K=512) for our 8 batch rows into LDS ----
            const bool zero2 = (layer == 0) ? (s == 0) : (s == 1);
            const float* p1 = (layer == 0)
                ? (x + (size_t)s * BH)
                : (h0buf + (size_t)((s + 2) % 3) * BH);   // h0[s-1]
            const float* p2 = (layer == 0)
                ? (h0buf + (size_t)((s + 2) % 3) * BH)    // h0[s-1]
                : (h1buf + (size_t)((s + 1) % 3) * BH);   // h1[s-2]
            #pragma unroll
            for (int i = 0; i < 4; ++i) {
                const int F = tid + 256 * i;     // f4 index in 8x128
                const int b = F >> 7;
                const int rr = F & 127;
                const int col = (rr & 63) * 4;
                float4 v;
                if ((rr >> 6) == 0) {
                    const float* src = p1 + (size_t)(Bg0 + b) * HID + col;
                    v = (layer == 0) ? ldf4(src) : af4(src);
                } else if (zero2) {
                    v = make_float4(0.f, 0.f, 0.f, 0.f);
                } else {
                    const float* src = p2 + (size_t)(Bg0 + b) * HID + col;
                    v = af4(src);
                }
                *(float4*)(ls_in + b * 576 + (rr >> 3) * 36 + (rr & 7) * 4) = v;
            }
        }
        __syncthreads();   // staging visible

        if (active) {
            const int t_s = (layer == 0) ? s : (s - 1);
            float* hst = ((layer == 0) ? h0buf : h1buf) + (size_t)(t_s % 3) * BH;
            const bool last = (layer == 0) ? (s == T_LEN - 1) : (s == T_LEN);
            #pragma unroll 1
            for (int b = 0; b < 8; ++b) {
                const float* Lp = ls_in + b * 576 + kc * 36;
                float4 in[8];
                #pragma unroll
                for (int m = 0; m < 8; ++m) in[m] = *(const float4*)(Lp + m * 4);
                float4 ac[4];
                #pragma unroll
                for (int g = 0; g < 4; ++g) ac[g] = make_float4(0.f, 0.f, 0.f, 0.f);
                #pragma unroll
                for (int m = 0; m < 8; ++m) {
                    #pragma unroll
                    for (int g = 0; g < 4; ++g) fma4(ac[g], in[m], w[g][m]);
                }
                float a0 = red16(hsum4(ac[0]));
                float a1 = red16(hsum4(ac[1]));
                float a2 = red16(hsum4(ac[2]));
                float a3 = red16(hsum4(ac[3]));
                if (kc == 15) {        // owner lane holds full K-sum
                    const int B = Bg0 + b;
                    const float gi = sigmoid_f(a0 + bias[0]);
                    const float gf = sigmoid_f(a1 + bias[1]);
                    const float gg = tanh_f   (a2 + bias[2]);
                    const float go = sigmoid_f(a3 + bias[3]);
                    const float cold = ls_c[b * 16 + jp];
                    const float cnew = fmaf(gf, cold, gi * gg);
                    ls_c[b * 16 + jp] = cnew;
                    const float h = go * tanh_f(cnew);
                    astore(hst + (size_t)B * HID + j, h);
                    if (layer == 1)
                        out[(size_t)t_s * BH + (size_t)B * HID + j] = h;
                    if (last) {
                        float* hn  = out + (size_t)T_LEN * BH;
                        float* cnp = hn + 2 * BH;
                        hn [(size_t)layer * BH + (size_t)B * HID + j] = h;
                        cnp[(size_t)layer * BH + (size_t)B * HID + j] = cnew;
                    }
                }
            }
        }
        __syncthreads();   // all waves' h-stores drained (vmcnt(0) before s_barrier)
        if (s < T_LEN && tid == 0)
            __hip_atomic_store(myflag, s + 1, __ATOMIC_RELAXED, __HIP_MEMORY_SCOPE_AGENT);
    }
}

extern "C" void kernel_launch(void* const* d_in, const int* in_sizes, int n_in,
                              void* d_out, int out_size, void* d_ws, size_t ws_size,
                              hipStream_t stream) {
    const float* x   = (const float*)d_in[0];
    const float* Wih = (const float*)d_in[1];
    const float* Whh = (const float*)d_in[2];
    const float* bih = (const float*)d_in[3];
    const float* bhh = (const float*)d_in[4];
    float* out = (float*)d_out;

    float* h0 = (float*)d_ws;          // 3*BH
    float* h1 = h0 + 3 * BH;           // 3*BH
    int* flags = (int*)(h1 + 3 * BH);  // 512 ints, poison-proof (signed compare)

    hipLaunchKernelGGL(lstm_persist, dim3(512), dim3(256), 0, stream,
                       x, Wih, Whh, bih, bhh, out, h0, h1, flags);
}

// Round 4
// 5223.562 us; speedup vs baseline: 9.8537x; 1.0178x over previous
//
#include <hip/hip_runtime.h>
#include <math.h>

#define T_LEN 512
#define BATCH 128
#define HID   256
#define BH    (BATCH*HID)   // 32768

// ---------------- helpers ----------------
__device__ __forceinline__ float sigmoid_f(float v) {
    return 1.f / (1.f + __expf(-v));
}
__device__ __forceinline__ float tanh_f(float v) {
    v = fminf(fmaxf(v, -15.f), 15.f);
    float e = __expf(2.f * v);
    return (e - 1.f) / (e + 1.f);
}
__device__ __forceinline__ float4 ldf4(const float* p) {
    return *reinterpret_cast<const float4*>(p);
}
__device__ __forceinline__ void fma4(float4& a, const float4 v, const float4 w) {
    a.x = fmaf(v.x, w.x, a.x);
    a.y = fmaf(v.y, w.y, a.y);
    a.z = fmaf(v.z, w.z, a.z);
    a.w = fmaf(v.w, w.w, a.w);
}
__device__ __forceinline__ float hsum4(const float4 a) {
    return (a.x + a.y) + (a.z + a.w);
}
// agent-scope relaxed atomics: coherent across XCDs, no cache flushes
__device__ __forceinline__ void astore(float* p, float v) {
    __hip_atomic_store(p, v, __ATOMIC_RELAXED, __HIP_MEMORY_SCOPE_AGENT);
}
__device__ __forceinline__ float2 af2(const float* p) {
    unsigned long long u = __hip_atomic_load((const unsigned long long*)p,
                                             __ATOMIC_RELAXED, __HIP_MEMORY_SCOPE_AGENT);
    union { unsigned long long u; float2 f; } c; c.u = u;
    return c.f;
}
__device__ __forceinline__ float4 af4(const float* p) {
    const float2 a = af2(p), b = af2(p + 2);
    return make_float4(a.x, a.y, b.x, b.y);
}
// DPP row_shr prefix reduction within 16-lane groups; lane (kc==15) gets the sum.
template<int CTRL>
__device__ __forceinline__ float dpp_mv(float x) {
    return __int_as_float(__builtin_amdgcn_update_dpp(
        0, __float_as_int(x), CTRL, 0xF, 0xF, true));
}
__device__ __forceinline__ float red16(float x) {
    x += dpp_mv<0x111>(x);  // row_shr:1
    x += dpp_mv<0x112>(x);  // row_shr:2
    x += dpp_mv<0x114>(x);  // row_shr:4
    x += dpp_mv<0x118>(x);  // row_shr:8
    return x;               // valid in lane kc==15 of each 16-group
}

// ---------------- persistent LSTM ----------------
// grid 512 x 256, 2 blocks/CU.
// amdgpu_waves_per_eu(2,2): pin the RA occupancy target to exactly 2 waves/EU
// (VGPR budget 256). Without this the scheduler chases higher occupancy and
// remats the weight loads into the step loop (R2: 168 VGPR, R3: 96 VGPR).
// bid: bg = bid&15 (8 batch rows), layer = (bid>>4)&1, jt = bid>>5 (16 j each).
// tid: jp = tid>>4 (one j per thread), kc = tid&15 (K-chunk of 32 in combined
// K=512: [0,256)=input/lower-layer h, [256,512)=own recurrent h).
// Weights: 4 gate rows x 32 floats = 128 VGPRs/thread, loaded once, pinned.
__global__ __launch_bounds__(256)
__attribute__((amdgpu_waves_per_eu(2, 2)))
void lstm_persist(
    const float* __restrict__ x,
    const float* __restrict__ Wih, const float* __restrict__ Whh,
    const float* __restrict__ bih, const float* __restrict__ bhh,
    float* __restrict__ out,
    float* __restrict__ h0buf,   // 3 * BH (triple-buffered by timestep%3)
    float* __restrict__ h1buf,   // 3 * BH
    int* __restrict__ flags)     // 16 groups x 32 blocks
{
    __shared__ float ls_in[8 * 576];   // 8 b x 16 chunks x 36 (pad -> 2-way alias = free)
    __shared__ float ls_c[128];        // c[b][jp]

    const int tid = threadIdx.x;
    const int bid = blockIdx.x;
    const int bg = bid & 15;
    const int layer = (bid >> 4) & 1;
    const int jt = bid >> 5;
    const int jp = tid >> 4;
    const int kc = tid & 15;
    const int j = jt * 16 + jp;
    const int Bg0 = bg * 8;

    const float* Wih_l = Wih + (size_t)layer * 4 * HID * HID;
    const float* Whh_l = Whh + (size_t)layer * 4 * HID * HID;
    const float* bih_l = bih + layer * 4 * HID;
    const float* bhh_l = bhh + layer * 4 * HID;

    float4 w[4][8];     // [gate][m] : 128 VGPRs
    float bias[4];
    #pragma unroll
    for (int g = 0; g < 4; ++g) {
        const int row = g * HID + j;             // row in 4H
        const float* base = (kc < 8)
            ? (Wih_l + (size_t)row * HID + kc * 32)
            : (Whh_l + (size_t)row * HID + (kc - 8) * 32);
        #pragma unroll
        for (int m = 0; m < 8; ++m) w[g][m] = ldf4(base + m * 4);
        bias[g] = bih_l[row] + bhh_l[row];
    }
    // May-write-anything barrier: re-loading w[][] after this point would be an
    // illegal transform, so the compiler must keep the values live in VGPRs.
    asm volatile("" ::: "memory");

    if (tid < 128) ls_c[tid] = 0.f;   // synced by first barrier below

    int* myflag = flags + bg * 32 + layer * 16 + jt;

    #pragma unroll 1
    for (int s = 0; s <= T_LEN; ++s) {
        if (s > 0 && tid < 32) {
            const int* f = flags + bg * 32 + tid;
            // signed compare: 0xAAAAAAAA poison is negative -> blocks until real store
            while (__hip_atomic_load(f, __ATOMIC_RELAXED, __HIP_MEMORY_SCOPE_AGENT) < s)
                __builtin_amdgcn_s_sleep(1);
        }
        __syncthreads();   // everyone past poll; h[s-1] published & visible

        const bool active = (layer == 0) ? (s < T_LEN) : (s >= 1);
        if (active) {
            // ---- stage [x|h] (combined K=512) for our 8 batch rows into LDS ----
            const bool zero2 = (layer == 0) ? (s == 0) : (s == 1);
            const float* p1 = (layer == 0)
                ? (x + (size_t)s * BH)
                : (h0buf + (size_t)((s + 2) % 3) * BH);   // h0[s-1]
            const float* p2 = (layer == 0)
                ? (h0buf + (size_t)((s + 2) % 3) * BH)    // h0[s-1]
                : (h1buf + (size_t)((s + 1) % 3) * BH);   // h1[s-2]
            #pragma unroll
            for (int i = 0; i < 4; ++i) {
                const int F = tid + 256 * i;     // f4 index in 8x128
                const int b = F >> 7;
                const int rr = F & 127;
                const int col = (rr & 63) * 4;
                float4 v;
                if ((rr >> 6) == 0) {
                    const float* src = p1 + (size_t)(Bg0 + b) * HID + col;
                    v = (layer == 0) ? ldf4(src) : af4(src);
                } else if (zero2) {
                    v = make_float4(0.f, 0.f, 0.f, 0.f);
                } else {
                    const float* src = p2 + (size_t)(Bg0 + b) * HID + col;
                    v = af4(src);
                }
                *(float4*)(ls_in + b * 576 + (rr >> 3) * 36 + (rr & 7) * 4) = v;
            }
        }
        __syncthreads();   // staging visible

        if (active) {
            const int t_s = (layer == 0) ? s : (s - 1);
            float* hst = ((layer == 0) ? h0buf : h1buf) + (size_t)(t_s % 3) * BH;
            const bool last = (layer == 0) ? (s == T_LEN - 1) : (s == T_LEN);
            #pragma unroll 1
            for (int b = 0; b < 8; ++b) {
                const float* Lp = ls_in + b * 576 + kc * 36;
                float4 in[8];
                #pragma unroll
                for (int m = 0; m < 8; ++m) in[m] = *(const float4*)(Lp + m * 4);
                float4 ac[4];
                #pragma unroll
                for (int g = 0; g < 4; ++g) ac[g] = make_float4(0.f, 0.f, 0.f, 0.f);
                #pragma unroll
                for (int m = 0; m < 8; ++m) {
                    #pragma unroll
                    for (int g = 0; g < 4; ++g) fma4(ac[g], in[m], w[g][m]);
                }
                float a0 = red16(hsum4(ac[0]));
                float a1 = red16(hsum4(ac[1]));
                float a2 = red16(hsum4(ac[2]));
                float a3 = red16(hsum4(ac[3]));
                if (kc == 15) {        // owner lane holds full K-sum
                    const int B = Bg0 + b;
                    const float gi = sigmoid_f(a0 + bias[0]);
                    const float gf = sigmoid_f(a1 + bias[1]);
                    const float gg = tanh_f   (a2 + bias[2]);
                    const float go = sigmoid_f(a3 + bias[3]);
                    const float cold = ls_c[b * 16 + jp];
                    const float cnew = fmaf(gf, cold, gi * gg);
                    ls_c[b * 16 + jp] = cnew;
                    const float h = go * tanh_f(cnew);
                    astore(hst + (size_t)B * HID + j, h);
                    if (layer == 1)
                        out[(size_t)t_s * BH + (size_t)B * HID + j] = h;
                    if (last) {
                        float* hn  = out + (size_t)T_LEN * BH;
                        float* cnp = hn + 2 * BH;
                        hn [(size_t)layer * BH + (size_t)B * HID + j] = h;
                        cnp[(size_t)layer * BH + (size_t)B * HID + j] = cnew;
                    }
                }
            }
        }
        __syncthreads();   // all waves' h-stores drained (vmcnt(0) before s_barrier)
        if (s < T_LEN && tid == 0)
            __hip_atomic_store(myflag, s + 1, __ATOMIC_RELAXED, __HIP_MEMORY_SCOPE_AGENT);
    }
}

extern "C" void kernel_launch(void* const* d_in, const int* in_sizes, int n_in,
                              void* d_out, int out_size, void* d_ws, size_t ws_size,
                              hipStream_t stream) {
    const float* x   = (const float*)d_in[0];
    const float* Wih = (const float*)d_in[1];
    const float* Whh = (const float*)d_in[2];
    const float* bih = (const float*)d_in[3];
    const float* bhh = (const float*)d_in[4];
    float* out = (float*)d_out;

    float* h0 = (float*)d_ws;          // 3*BH
    float* h1 = h0 + 3 * BH;           // 3*BH
    int* flags = (int*)(h1 + 3 * BH);  // 512 ints, poison-proof (signed compare)

    hipLaunchKernelGGL(lstm_persist, dim3(512), dim3(256), 0, stream,
                       x, Wih, Whh, bih, bhh, out, h0, h1, flags);
}

// Round 5
// 3720.248 us; speedup vs baseline: 13.8355x; 1.4041x over previous
//
#include <hip/hip_runtime.h>
#include <math.h>

#define T_LEN 512
#define BATCH 128
#define HID   256
#define BH    (BATCH*HID)   // 32768

// ---------------- helpers ----------------
__device__ __forceinline__ float sigmoid_f(float v) {
    return 1.f / (1.f + __expf(-v));
}
__device__ __forceinline__ float tanh_f(float v) {
    v = fminf(fmaxf(v, -15.f), 15.f);
    float e = __expf(2.f * v);
    return (e - 1.f) / (e + 1.f);
}
__device__ __forceinline__ float4 ldf4(const float* p) {
    return *reinterpret_cast<const float4*>(p);
}
__device__ __forceinline__ void fma4(float4& a, const float4 v, const float4 w) {
    a.x = fmaf(v.x, w.x, a.x);
    a.y = fmaf(v.y, w.y, a.y);
    a.z = fmaf(v.z, w.z, a.z);
    a.w = fmaf(v.w, w.w, a.w);
}
__device__ __forceinline__ float hsum4(const float4 a) {
    return (a.x + a.y) + (a.z + a.w);
}
// Pin a value into a VGPR: producer becomes volatile asm -> the original
// global load can no longer be sunk/rematerialized into the step loop.
__device__ __forceinline__ void pin4(float4& v) {
    asm volatile("" : "+v"(v.x), "+v"(v.y), "+v"(v.z), "+v"(v.w));
}
// agent-scope relaxed atomics: coherent across XCDs, no cache flushes
__device__ __forceinline__ void astore(float* p, float v) {
    __hip_atomic_store(p, v, __ATOMIC_RELAXED, __HIP_MEMORY_SCOPE_AGENT);
}
__device__ __forceinline__ float2 af2(const float* p) {
    unsigned long long u = __hip_atomic_load((const unsigned long long*)p,
                                             __ATOMIC_RELAXED, __HIP_MEMORY_SCOPE_AGENT);
    union { unsigned long long u; float2 f; } c; c.u = u;
    return c.f;
}
__device__ __forceinline__ float4 af4(const float* p) {
    const float2 a = af2(p), b = af2(p + 2);
    return make_float4(a.x, a.y, b.x, b.y);
}
// DPP row_shr prefix reduction within 16-lane groups; lane (kc==15) gets the sum.
template<int CTRL>
__device__ __forceinline__ float dpp_mv(float x) {
    return __int_as_float(__builtin_amdgcn_update_dpp(
        0, __float_as_int(x), CTRL, 0xF, 0xF, true));
}
__device__ __forceinline__ float red16(float x) {
    x += dpp_mv<0x111>(x);  // row_shr:1
    x += dpp_mv<0x112>(x);  // row_shr:2
    x += dpp_mv<0x114>(x);  // row_shr:4
    x += dpp_mv<0x118>(x);  // row_shr:8
    return x;               // valid in lane kc==15 of each 16-group
}

// ---------------- persistent LSTM ----------------
// grid 512 x 256, 2 blocks/CU, waves_per_eu(2,2) -> 256-VGPR budget.
// bid: bg = bid&15 (8 batch rows), layer = (bid>>4)&1, jt = bid>>5 (16 j each).
// tid: jp = tid>>4 (one j per thread), kc = tid&15 (K-chunk of 32 in combined
// K=512: [0,256)=input/lower-layer h, [256,512)=own recurrent h).
// Weights: 4 gate rows x 32 floats = 128 VGPRs/thread, loaded once, PINNED via
// per-component volatile asm (R2-R4 showed the scheduler otherwise sinks the
// invariant loads back into the step loop: VGPR 168/96/108, ~3x VALU excess).
__global__ __launch_bounds__(256)
__attribute__((amdgpu_waves_per_eu(2, 2)))
void lstm_persist(
    const float* __restrict__ x,
    const float* __restrict__ Wih, const float* __restrict__ Whh,
    const float* __restrict__ bih, const float* __restrict__ bhh,
    float* __restrict__ out,
    float* __restrict__ h0buf,   // 3 * BH (triple-buffered by timestep%3)
    float* __restrict__ h1buf,   // 3 * BH
    int* __restrict__ flags)     // 16 groups x 32 blocks
{
    __shared__ float ls_in[8 * 576];   // 8 b x 16 chunks x 36 (pad -> 2-way alias = free)
    __shared__ float ls_c[128];        // c[b*16+jp]
    __shared__ float ls_a[128 * 4];    // gate pre-activations [b*16+jp][g]

    const int tid = threadIdx.x;
    const int bid = blockIdx.x;
    const int bg = bid & 15;
    const int layer = (bid >> 4) & 1;
    const int jt = bid >> 5;
    const int jp = tid >> 4;
    const int kc = tid & 15;
    const int j = jt * 16 + jp;
    const int Bg0 = bg * 8;

    const float* Wih_l = Wih + (size_t)layer * 4 * HID * HID;
    const float* Whh_l = Whh + (size_t)layer * 4 * HID * HID;
    const float* bih_l = bih + layer * 4 * HID;
    const float* bhh_l = bhh + layer * 4 * HID;

    float4 w[4][8];     // [gate][m] : 128 VGPRs, pinned
    float bias[4];
    #pragma unroll
    for (int g = 0; g < 4; ++g) {
        const int row = g * HID + j;             // row in 4H
        const float* base = (kc < 8)
            ? (Wih_l + (size_t)row * HID + kc * 32)
            : (Whh_l + (size_t)row * HID + (kc - 8) * 32);
        #pragma unroll
        for (int m = 0; m < 8; ++m) {
            w[g][m] = ldf4(base + m * 4);
            pin4(w[g][m]);
        }
        bias[g] = bih_l[row] + bhh_l[row];
        asm volatile("" : "+v"(bias[g]));
    }

    if (tid < 128) ls_c[tid] = 0.f;   // synced by first barrier below

    int* myflag = flags + bg * 32 + layer * 16 + jt;

    #pragma unroll 1
    for (int s = 0; s <= T_LEN; ++s) {
        if (s > 0 && tid < 32) {
            const int* f = flags + bg * 32 + tid;
            // signed compare: 0xAAAAAAAA poison is negative -> blocks until real store
            while (__hip_atomic_load(f, __ATOMIC_RELAXED, __HIP_MEMORY_SCOPE_AGENT) < s)
                __builtin_amdgcn_s_sleep(1);
        }
        __syncthreads();   // everyone past poll; h[s-1] published & visible

        const bool active = (layer == 0) ? (s < T_LEN) : (s >= 1);
        if (active) {
            // ---- stage [x|h] (combined K=512) for our 8 batch rows into LDS ----
            const bool zero2 = (layer == 0) ? (s == 0) : (s == 1);
            const float* p1 = (layer == 0)
                ? (x + (size_t)s * BH)
                : (h0buf + (size_t)((s + 2) % 3) * BH);   // h0[s-1]
            const float* p2 = (layer == 0)
                ? (h0buf + (size_t)((s + 2) % 3) * BH)    // h0[s-1]
                : (h1buf + (size_t)((s + 1) % 3) * BH);   // h1[s-2]
            #pragma unroll
            for (int i = 0; i < 4; ++i) {
                const int F = tid + 256 * i;     // f4 index in 8x128
                const int b = F >> 7;
                const int rr = F & 127;
                const int col = (rr & 63) * 4;
                float4 v;
                if ((rr >> 6) == 0) {
                    const float* src = p1 + (size_t)(Bg0 + b) * HID + col;
                    v = (layer == 0) ? ldf4(src) : af4(src);
                } else if (zero2) {
                    v = make_float4(0.f, 0.f, 0.f, 0.f);
                } else {
                    const float* src = p2 + (size_t)(Bg0 + b) * HID + col;
                    v = af4(src);
                }
                *(float4*)(ls_in + b * 576 + (rr >> 3) * 36 + (rr & 7) * 4) = v;
            }
        }
        __syncthreads();   // staging visible

        if (active) {
            // ---- gate GEMV: each thread K-chunk of 32, reduce over 16 lanes ----
            #pragma unroll 1
            for (int b = 0; b < 8; ++b) {
                const float* Lp = ls_in + b * 576 + kc * 36;
                float4 in[8];
                #pragma unroll
                for (int m = 0; m < 8; ++m) in[m] = *(const float4*)(Lp + m * 4);
                float4 ac[4];
                #pragma unroll
                for (int g = 0; g < 4; ++g) ac[g] = make_float4(0.f, 0.f, 0.f, 0.f);
                #pragma unroll
                for (int m = 0; m < 8; ++m) {
                    #pragma unroll
                    for (int g = 0; g < 4; ++g) fma4(ac[g], in[m], w[g][m]);
                }
                float a0 = red16(hsum4(ac[0]));
                float a1 = red16(hsum4(ac[1]));
                float a2 = red16(hsum4(ac[2]));
                float a3 = red16(hsum4(ac[3]));
                if (kc == 15) {        // owner lane: publish pre-activations (+bias)
                    float* ap = ls_a + (b * 16 + jp) * 4;
                    ap[0] = a0 + bias[0];
                    ap[1] = a1 + bias[1];
                    ap[2] = a2 + bias[2];
                    ap[3] = a3 + bias[3];
                }
            }
        }
        __syncthreads();   // ls_a complete

        if (active && tid < 128) {
            // ---- all-lane epilogue: thread = one (b, j) cell ----
            const int bb = tid >> 4;
            const int jpp = tid & 15;
            const int t_s = (layer == 0) ? s : (s - 1);
            float* hst = ((layer == 0) ? h0buf : h1buf) + (size_t)(t_s % 3) * BH;
            const bool last = (layer == 0) ? (s == T_LEN - 1) : (s == T_LEN);
            const float* ap = ls_a + tid * 4;
            const float gi = sigmoid_f(ap[0]);
            const float gf = sigmoid_f(ap[1]);
            const float gg = tanh_f   (ap[2]);
            const float go = sigmoid_f(ap[3]);
            const float cold = ls_c[tid];
            const float cnew = fmaf(gf, cold, gi * gg);
            ls_c[tid] = cnew;
            const float h = go * tanh_f(cnew);
            const int B = Bg0 + bb;
            const int jg = jt * 16 + jpp;
            astore(hst + (size_t)B * HID + jg, h);
            if (layer == 1)
                out[(size_t)t_s * BH + (size_t)B * HID + jg] = h;
            if (last) {
                float* hn  = out + (size_t)T_LEN * BH;
                float* cnp = hn + 2 * BH;
                hn [(size_t)layer * BH + (size_t)B * HID + jg] = h;
                cnp[(size_t)layer * BH + (size_t)B * HID + jg] = cnew;
            }
        }
        __syncthreads();   // h-stores drained (vmcnt(0) before s_barrier)
        if (s < T_LEN && tid == 0)
            __hip_atomic_store(myflag, s + 1, __ATOMIC_RELAXED, __HIP_MEMORY_SCOPE_AGENT);
    }
}

extern "C" void kernel_launch(void* const* d_in, const int* in_sizes, int n_in,
                              void* d_out, int out_size, void* d_ws, size_t ws_size,
                              hipStream_t stream) {
    const float* x   = (const float*)d_in[0];
    const float* Wih = (const float*)d_in[1];
    const float* Whh = (const float*)d_in[2];
    const float* bih = (const float*)d_in[3];
    const float* bhh = (const float*)d_in[4];
    float* out = (float*)d_out;

    float* h0 = (float*)d_ws;          // 3*BH
    float* h1 = h0 + 3 * BH;           // 3*BH
    int* flags = (int*)(h1 + 3 * BH);  // 512 ints, poison-proof (signed compare)

    hipLaunchKernelGGL(lstm_persist, dim3(512), dim3(256), 0, stream,
                       x, Wih, Whh, bih, bhh, out, h0, h1, flags);
}